// Round 7
// baseline (287.008 us; speedup 1.0000x reference)
//
#include <hip/hip_runtime.h>

#define N_PIX   32768
#define DIM     64
#define K_CODES 1024
#define NCHUNK  8
#define CHUNK   (K_CODES / NCHUNK)   // 128

// ws layout:
//   [0, 4096)                 : c2[1024] (float)
//   [4096, +2 MiB)            : partials float2[NCHUNK][N_PIX]
//   [4096 + 2 MiB, +128 KiB)  : idx[N_PIX] (int)

__global__ __launch_bounds__(256) void c2_kernel(const float* __restrict__ cb,
                                                 float* __restrict__ c2) {
    int k = blockIdx.x * 256 + threadIdx.x;
    if (k >= K_CODES) return;
    const float* row = cb + k * DIM;
    float a0 = 0.f, a1 = 0.f, a2 = 0.f, a3 = 0.f;
#pragma unroll
    for (int d = 0; d < DIM; d += 4) {
        a0 = fmaf(row[d + 0], row[d + 0], a0);
        a1 = fmaf(row[d + 1], row[d + 1], a1);
        a2 = fmaf(row[d + 2], row[d + 2], a2);
        a3 = fmaf(row[d + 3], row[d + 3], a3);
    }
    c2[k] = (a0 + a1) + (a2 + a3);
}

// P=4 pixels/thread. Block = 256 threads x 4 pixels = 1024 pixels x 128 codes.
// grid = 32 pixblk x 8 chunks = 256 blocks = exactly 1 block/CU.
// Rounds 4/5 proved the kernel is DS-pipe-bound: 16 broadcast ds_read_b128 per
// row serve only 64 lane-pairs -> 123/P us. P=4 balances DS (~31us) with VALU
// (~32us). 256 x-floats live -> ~320 VGPR, 1 wave/SIMD, launch_bounds(256,1).
__global__ __launch_bounds__(256, 1) void argmin_lds(const float* __restrict__ x,
                                                     const float* __restrict__ cb,
                                                     const float* __restrict__ c2,
                                                     float2* __restrict__ part) {
    __shared__ alignas(16) float4 lds_cb[CHUNK * (DIM / 4)];   // 32 KB
    __shared__ float lds_c2[CHUNK];                            // 512 B

    int blk    = blockIdx.x;
    int pixblk = blk >> 3;       // 0..31  == batch index bb
    int chunk  = blk & 7;        // 0..7
    int t  = threadIdx.x;
    int k0 = chunk * CHUNK;

    // Stage codebook chunk: 2048 float4s, 8 per thread, coalesced.
    {
        const float4* cb4 = reinterpret_cast<const float4*>(cb) + (size_t)k0 * (DIM / 4);
#pragma unroll
        for (int i = 0; i < 8; ++i)
            lds_cb[t + i * 256] = cb4[t + i * 256];
        if (t < CHUNK) lds_c2[t] = c2[k0 + t];
    }

    // 4 pixels: p_i = pixblk*1024 + t + i*256 ; bb = pixblk ; hw = t + i*256.
    const float* xb0 = x + (size_t)pixblk * (DIM * 1024) + t;
    const float* xb1 = xb0 + 256;
    const float* xb2 = xb0 + 512;
    const float* xb3 = xb0 + 768;

#define LDX(b, i) make_float4(b[(size_t)(4*(i)+0) << 10], b[(size_t)(4*(i)+1) << 10], \
                              b[(size_t)(4*(i)+2) << 10], b[(size_t)(4*(i)+3) << 10])
#define DECLX(p, b) \
    float4 x##p##_0 = LDX(b,0),  x##p##_1 = LDX(b,1),  x##p##_2 = LDX(b,2),  x##p##_3 = LDX(b,3), \
           x##p##_4 = LDX(b,4),  x##p##_5 = LDX(b,5),  x##p##_6 = LDX(b,6),  x##p##_7 = LDX(b,7), \
           x##p##_8 = LDX(b,8),  x##p##_9 = LDX(b,9),  x##p##_10 = LDX(b,10), x##p##_11 = LDX(b,11), \
           x##p##_12 = LDX(b,12), x##p##_13 = LDX(b,13), x##p##_14 = LDX(b,14), x##p##_15 = LDX(b,15);
    DECLX(0, xb0) DECLX(1, xb1) DECLX(2, xb2) DECLX(3, xb3)
#undef LDX
#undef DECLX

    // Squared norm per pixel (named xn# to avoid colliding with fragments
    // x{p}_{i} — round 6's compile failure). Identical reduction tree to the
    // verified rounds: s0..s3 accumulate d%4==0..3 ascending, (s0+s1)+(s2+s3).
#define SQ(v) { s0 = fmaf(v.x, v.x, s0); s1 = fmaf(v.y, v.y, s1); \
                s2 = fmaf(v.z, v.z, s2); s3 = fmaf(v.w, v.w, s3); }
#define XNORM(p) float xn##p; { float s0=0.f,s1=0.f,s2=0.f,s3=0.f; \
    SQ(x##p##_0) SQ(x##p##_1) SQ(x##p##_2) SQ(x##p##_3) \
    SQ(x##p##_4) SQ(x##p##_5) SQ(x##p##_6) SQ(x##p##_7) \
    SQ(x##p##_8) SQ(x##p##_9) SQ(x##p##_10) SQ(x##p##_11) \
    SQ(x##p##_12) SQ(x##p##_13) SQ(x##p##_14) SQ(x##p##_15) \
    xn##p = (s0 + s1) + (s2 + s3); }
    XNORM(0) XNORM(1) XNORM(2) XNORM(3)
#undef XNORM
#undef SQ

    __syncthreads();

    // Pin every x fragment into VGPRs here so the compiler cannot
    // rematerialize them as global reloads inside the k-loop (proven round 5).
#define PIN(v) asm volatile("" : "+v"(v.x), "+v"(v.y), "+v"(v.z), "+v"(v.w));
#define PINP(p) PIN(x##p##_0) PIN(x##p##_1) PIN(x##p##_2) PIN(x##p##_3) \
                PIN(x##p##_4) PIN(x##p##_5) PIN(x##p##_6) PIN(x##p##_7) \
                PIN(x##p##_8) PIN(x##p##_9) PIN(x##p##_10) PIN(x##p##_11) \
                PIN(x##p##_12) PIN(x##p##_13) PIN(x##p##_14) PIN(x##p##_15)
    PINP(0) PINP(1) PINP(2) PINP(3)
#undef PINP
#undef PIN

    float best0 = 1e30f, best1 = 1e30f, best2 = 1e30f, best3 = 1e30f;
    int   bi0 = 0, bi1 = 0, bi2 = 0, bi3 = 0;

#define FMA_PIX(p, i, w) \
    a##p##_0 = fmaf(x##p##_##i.x, w.x, a##p##_0); \
    a##p##_1 = fmaf(x##p##_##i.y, w.y, a##p##_1); \
    a##p##_2 = fmaf(x##p##_##i.z, w.z, a##p##_2); \
    a##p##_3 = fmaf(x##p##_##i.w, w.w, a##p##_3);
#define STEP(i) { float4 w = wrow[i]; \
    FMA_PIX(0, i, w) FMA_PIX(1, i, w) FMA_PIX(2, i, w) FMA_PIX(3, i, w) }

    for (int kk = 0; kk < CHUNK; ++kk) {
        const float4* wrow = &lds_cb[kk * (DIM / 4)];   // uniform addr -> broadcast
        float c2k = lds_c2[kk];
        float a0_0 = 0.f, a0_1 = 0.f, a0_2 = 0.f, a0_3 = 0.f;
        float a1_0 = 0.f, a1_1 = 0.f, a1_2 = 0.f, a1_3 = 0.f;
        float a2_0 = 0.f, a2_1 = 0.f, a2_2 = 0.f, a2_3 = 0.f;
        float a3_0 = 0.f, a3_1 = 0.f, a3_2 = 0.f, a3_3 = 0.f;
        STEP(0)  STEP(1)  STEP(2)  STEP(3)
        STEP(4)  STEP(5)  STEP(6)  STEP(7)
        STEP(8)  STEP(9)  STEP(10) STEP(11)
        STEP(12) STEP(13) STEP(14) STEP(15)
        // Reference rounding: d2 = (x2 - 2*dot) + c2 — ulp-64 grid quantization
        // stabilizes tie-breaking (verified exact, rounds 2-5).
        float dot0 = (a0_0 + a0_1) + (a0_2 + a0_3);
        float dot1 = (a1_0 + a1_1) + (a1_2 + a1_3);
        float dot2 = (a2_0 + a2_1) + (a2_2 + a2_3);
        float dot3 = (a3_0 + a3_1) + (a3_2 + a3_3);
        float d0 = (xn0 - 2.0f * dot0) + c2k;
        float d1 = (xn1 - 2.0f * dot1) + c2k;
        float d2 = (xn2 - 2.0f * dot2) + c2k;
        float d3 = (xn3 - 2.0f * dot3) + c2k;
        int k = k0 + kk;
        if (d0 < best0) { best0 = d0; bi0 = k; }   // strict <: first-min ties
        if (d1 < best1) { best1 = d1; bi1 = k; }
        if (d2 < best2) { best2 = d2; bi2 = k; }
        if (d3 < best3) { best3 = d3; bi3 = k; }
    }
#undef STEP
#undef FMA_PIX

    int p0 = pixblk * 1024 + t;
    float2 r;
    r.x = best0; r.y = __int_as_float(bi0); part[(size_t)chunk * N_PIX + p0      ] = r;
    r.x = best1; r.y = __int_as_float(bi1); part[(size_t)chunk * N_PIX + p0 + 256] = r;
    r.x = best2; r.y = __int_as_float(bi2); part[(size_t)chunk * N_PIX + p0 + 512] = r;
    r.x = best3; r.y = __int_as_float(bi3); part[(size_t)chunk * N_PIX + p0 + 768] = r;
}

// Reduce the NCHUNK partials per pixel (ascending chunk, strict < = first-min),
// store idx, and write quantized [B, D, H, W]. grid = 256 blocks x 128.
__global__ __launch_bounds__(128) void reduce_quant(const float* __restrict__ cb,
                                                    const float2* __restrict__ part,
                                                    int* __restrict__ idx,
                                                    float* __restrict__ quant) {
    int n = blockIdx.x * 128 + threadIdx.x;
    float best = 1e30f;
    int   bi = 0;
#pragma unroll
    for (int c = 0; c < NCHUNK; ++c) {
        float2 r = part[(size_t)c * N_PIX + n];
        if (r.x < best) { best = r.x; bi = __float_as_int(r.y); }
    }
    idx[n] = bi;

    int bb = n >> 10;
    int hw = n & 1023;
    const float4* crow = reinterpret_cast<const float4*>(cb + (size_t)bi * DIM);
    float* qb = quant + (size_t)bb * (DIM * 1024) + hw;
#pragma unroll
    for (int dq = 0; dq < 16; ++dq) {
        float4 cv = crow[dq];            // L2-resident gather
        qb[(size_t)(dq * 4 + 0) << 10] = cv.x;   // consecutive hw lanes -> coalesced
        qb[(size_t)(dq * 4 + 1) << 10] = cv.y;
        qb[(size_t)(dq * 4 + 2) << 10] = cv.z;
        qb[(size_t)(dq * 4 + 3) << 10] = cv.w;
    }
}

// Streaming one-hot writer: flat float4 index e covers enc[n][j0..j0+3],
// n = e>>8, j0 = (e&255)*4. grid-stride, 2048 blocks.
__global__ __launch_bounds__(256) void enc_write(const int* __restrict__ idx,
                                                 float* __restrict__ enc) {
    const int TOT = (N_PIX / 4) * K_CODES;   // 8388608 float4s
    int tid = blockIdx.x * 256 + threadIdx.x;
    float4* enc4 = reinterpret_cast<float4*>(enc);
    for (int e = tid; e < TOT; e += 2048 * 256) {
        int n  = e >> 8;
        int j0 = (e & 255) << 2;
        int ir = idx[n];                 // row-uniform -> L1/L2 broadcast
        float4 v;
        v.x = (ir == j0 + 0) ? 1.0f : 0.0f;
        v.y = (ir == j0 + 1) ? 1.0f : 0.0f;
        v.z = (ir == j0 + 2) ? 1.0f : 0.0f;
        v.w = (ir == j0 + 3) ? 1.0f : 0.0f;
        enc4[e] = v;
    }
}

extern "C" void kernel_launch(void* const* d_in, const int* in_sizes, int n_in,
                              void* d_out, int out_size, void* d_ws, size_t ws_size,
                              hipStream_t stream) {
    const float* x  = (const float*)d_in[0];
    const float* cb = (const float*)d_in[1];

    float*  c2   = (float*)d_ws;
    float2* part = (float2*)((char*)d_ws + 4096);
    int*    idx  = (int*)((char*)d_ws + 4096 + (size_t)NCHUNK * N_PIX * 8);

    float* enc   = (float*)d_out;                           // [32768, 1024]
    float* quant = (float*)d_out + (size_t)N_PIX * K_CODES; // [32, 64, 32, 32]

    c2_kernel<<<K_CODES / 256, 256, 0, stream>>>(cb, c2);
    argmin_lds<<<(N_PIX / 1024) * NCHUNK, 256, 0, stream>>>(x, cb, c2, part);
    reduce_quant<<<N_PIX / 128, 128, 0, stream>>>(cb, part, idx, quant);
    enc_write<<<2048, 256, 0, stream>>>(idx, enc);
}

// Round 8
// 208.943 us; speedup vs baseline: 1.3736x; 1.3736x over previous
//
#include <hip/hip_runtime.h>

#define N_PIX    32768
#define DIM      64
#define K_CODES  1024
#define NCHUNK   4
#define CHUNK    256          // codes per chunk
#define BPIX     128          // pixels per block
#define CS_STR   260          // cs row stride in floats (256 + 4 pad; rows 16B-aligned)

// ws layout: [0,4096) c2[1024] ; [4096, +128KiB) idx[N_PIX]

__global__ __launch_bounds__(256) void c2_kernel(const float* __restrict__ cb,
                                                 float* __restrict__ c2) {
    int k = blockIdx.x * 256 + threadIdx.x;
    if (k >= K_CODES) return;
    const float* row = cb + k * DIM;
    float a0 = 0.f, a1 = 0.f, a2 = 0.f, a3 = 0.f;
#pragma unroll
    for (int d = 0; d < DIM; d += 4) {
        a0 = fmaf(row[d + 0], row[d + 0], a0);
        a1 = fmaf(row[d + 1], row[d + 1], a1);
        a2 = fmaf(row[d + 2], row[d + 2], a2);
        a3 = fmaf(row[d + 3], row[d + 3], a3);
    }
    c2[k] = (a0 + a1) + (a2 + a3);
}

// Register-tiled GEMM-argmin. Block = 512 threads (8 waves, 2/SIMD), tile =
// 128 pixels x 1024 codes (4 chunks of 256). Thread tile 8x8, 1-float acc.
// Per d: 4 ds_read_b128 : 64 FMA (DS 48cyc : VALU 128cyc). Waves are 8wy x 8wx
// so frag reads are 2-way bank aliases (free). Fuses idx + quant writes.
__global__ __launch_bounds__(512, 2) void argmin_tile(const float* __restrict__ x,
                                                      const float* __restrict__ cb,
                                                      const float* __restrict__ c2,
                                                      int* __restrict__ idx,
                                                      float* __restrict__ quant) {
    __shared__ alignas(16) float xs[DIM * BPIX];     // 32 KB, [d][p]
    __shared__ alignas(16) float cs[DIM * CS_STR];   // 66.6 KB, [d][k] (+pad)
    __shared__ float  xn[BPIX];                      // 512 B
    __shared__ float2 red[4][BPIX];                  // 4 KB

    const int t      = threadIdx.x;
    const int blk    = blockIdx.x;
    const int p_base = blk * BPIX;        // 128 | 1024 -> never crosses batch
    const int bb     = p_base >> 10;
    const int hw0    = p_base & 1023;

    const float4* x4  = reinterpret_cast<const float4*>(x);
    const float4* cb4 = reinterpret_cast<const float4*>(cb);

    // ---- stage xs: x[bb][d][hw0..hw0+128) rows are contiguous (d-major free!)
#pragma unroll
    for (int i = 0; i < 4; ++i) {
        int fidx = i * 512 + t;           // 0..2047
        int d = fidx >> 5, p4 = fidx & 31;
        float4 v = x4[(size_t)bb * 16384 + (size_t)d * 256 + (hw0 >> 2) + p4];
        *reinterpret_cast<float4*>(&xs[d * BPIX + p4 * 4]) = v;   // contiguous rows
    }
    __syncthreads();

    // ---- xn per pixel: EXACT tree of the passing rounds (s[d%4], ascending,
    // then (s0+s1)+(s2+s3)).
    if (t < BPIX) {
        float s0 = 0.f, s1 = 0.f, s2 = 0.f, s3 = 0.f;
#pragma unroll
        for (int d = 0; d < DIM; d += 4) {
            float v0 = xs[(d + 0) * BPIX + t];
            float v1 = xs[(d + 1) * BPIX + t];
            float v2 = xs[(d + 2) * BPIX + t];
            float v3 = xs[(d + 3) * BPIX + t];
            s0 = fmaf(v0, v0, s0);
            s1 = fmaf(v1, v1, s1);
            s2 = fmaf(v2, v2, s2);
            s3 = fmaf(v3, v3, s3);
        }
        xn[t] = (s0 + s1) + (s2 + s3);
    }

    // ---- wave decomposition: 8 waves = (wr 0..1) x (wc 0..3); lane = 8wy x 8wx
    const int lane = t & 63, w = t >> 6;
    const int wy = lane >> 3, wx = lane & 7;
    const int wr = w >> 2,    wc = w & 3;
    const int pl0 = wr * 64 + wy * 8;     // local pixel base (0..120)
    const int kl0 = wc * 64 + wx * 8;     // local code base within chunk

    float bv[8]; int bk[8]; float xnr[8];
#pragma unroll
    for (int i = 0; i < 8; ++i) { bv[i] = 1e30f; bk[i] = 0; }

    // ---- prefetch chunk 0 c-tile to regs (fidx = dq*256 + k: k lane-fast ->
    // conflict-free LDS writes; global reads strided 256B but cb is L2/L3-hot)
    float4 creg[8];
#pragma unroll
    for (int i = 0; i < 8; ++i) {
        int fidx = i * 512 + t; int k = fidx & 255, dq = fidx >> 8;
        creg[i] = cb4[(size_t)k * 16 + dq];
    }
    __syncthreads();                      // xn ready

#pragma unroll
    for (int i = 0; i < 8; ++i) xnr[i] = xn[pl0 + i];

    for (int c = 0; c < NCHUNK; ++c) {
        // write staged chunk to cs (d-major transpose; banks = k%32, 2-way)
#pragma unroll
        for (int i = 0; i < 8; ++i) {
            int fidx = i * 512 + t; int k = fidx & 255, dq = fidx >> 8;
            cs[(4 * dq + 0) * CS_STR + k] = creg[i].x;
            cs[(4 * dq + 1) * CS_STR + k] = creg[i].y;
            cs[(4 * dq + 2) * CS_STR + k] = creg[i].z;
            cs[(4 * dq + 3) * CS_STR + k] = creg[i].w;
        }
        // issue next chunk's global loads (latency hides under compute)
        if (c + 1 < NCHUNK) {
#pragma unroll
            for (int i = 0; i < 8; ++i) {
                int fidx = i * 512 + t; int k = fidx & 255, dq = fidx >> 8;
                creg[i] = cb4[(size_t)((c + 1) * CHUNK + k) * 16 + dq];
            }
        }
        __syncthreads();

        float acc[8][8];
#pragma unroll
        for (int i = 0; i < 8; ++i)
#pragma unroll
            for (int j = 0; j < 8; ++j) acc[i][j] = 0.f;

#pragma unroll 4
        for (int d = 0; d < DIM; ++d) {
            const float* xr = &xs[d * BPIX + pl0];
            const float* cr = &cs[d * CS_STR + kl0];
            float4 xlo = *reinterpret_cast<const float4*>(xr);
            float4 xhi = *reinterpret_cast<const float4*>(xr + 4);
            float4 clo = *reinterpret_cast<const float4*>(cr);
            float4 chi = *reinterpret_cast<const float4*>(cr + 4);
#define ROW(i, xi) \
            acc[i][0] = fmaf(xi, clo.x, acc[i][0]); \
            acc[i][1] = fmaf(xi, clo.y, acc[i][1]); \
            acc[i][2] = fmaf(xi, clo.z, acc[i][2]); \
            acc[i][3] = fmaf(xi, clo.w, acc[i][3]); \
            acc[i][4] = fmaf(xi, chi.x, acc[i][4]); \
            acc[i][5] = fmaf(xi, chi.y, acc[i][5]); \
            acc[i][6] = fmaf(xi, chi.z, acc[i][6]); \
            acc[i][7] = fmaf(xi, chi.w, acc[i][7]);
            ROW(0, xlo.x) ROW(1, xlo.y) ROW(2, xlo.z) ROW(3, xlo.w)
            ROW(4, xhi.x) ROW(5, xhi.y) ROW(6, xhi.z) ROW(7, xhi.w)
#undef ROW
        }

        // chunk epilogue: quantized dist (reference rounding: (xn-2dot)+c2,
        // verified exact rounds 2-7), strict < ascending k = first-min ties.
        float4 c2lo = *reinterpret_cast<const float4*>(&c2[c * CHUNK + kl0]);
        float4 c2hi = *reinterpret_cast<const float4*>(&c2[c * CHUNK + kl0 + 4]);
        float c2a[8] = {c2lo.x, c2lo.y, c2lo.z, c2lo.w, c2hi.x, c2hi.y, c2hi.z, c2hi.w};
#pragma unroll
        for (int i = 0; i < 8; ++i) {
#pragma unroll
            for (int j = 0; j < 8; ++j) {
                int   k    = c * CHUNK + kl0 + j;
                float u    = xnr[i] - 2.0f * acc[i][j];
                float dist = u + c2a[j];
                if (dist < bv[i]) { bv[i] = dist; bk[i] = k; }
            }
        }
        __syncthreads();   // protect cs before next chunk's overwrite
    }

    // ---- cross-wx shuffle reduce (lex (val,k): equals global first-min)
#pragma unroll
    for (int i = 0; i < 8; ++i) {
#pragma unroll
        for (int off = 1; off <= 4; off <<= 1) {
            float ov = __shfl_xor(bv[i], off);
            int   ok = __shfl_xor(bk[i], off);
            if (ov < bv[i] || (ov == bv[i] && ok < bk[i])) { bv[i] = ov; bk[i] = ok; }
        }
    }
    if (wx == 0) {
#pragma unroll
        for (int i = 0; i < 8; ++i)
            red[wc][pl0 + i] = make_float2(bv[i], __int_as_float(bk[i]));
    }
    __syncthreads();

    // ---- final merge + idx + quant (fused; no partials kernel)
    if (t < BPIX) {
        float fv = 1e30f; int fk = 0;
#pragma unroll
        for (int cc = 0; cc < 4; ++cc) {
            float2 r  = red[cc][t];
            int    rk = __float_as_int(r.y);
            if (r.x < fv || (r.x == fv && rk < fk)) { fv = r.x; fk = rk; }
        }
        idx[p_base + t] = fk;

        const float4* crow = cb4 + (size_t)fk * 16;     // L2-resident gather
        float* qb = quant + (size_t)bb * (DIM * 1024) + (hw0 + t);
#pragma unroll
        for (int dq = 0; dq < 16; ++dq) {
            float4 cv = crow[dq];
            qb[(size_t)(dq * 4 + 0) << 10] = cv.x;      // consecutive t -> coalesced
            qb[(size_t)(dq * 4 + 1) << 10] = cv.y;
            qb[(size_t)(dq * 4 + 2) << 10] = cv.z;
            qb[(size_t)(dq * 4 + 3) << 10] = cv.w;
        }
    }
}

// Streaming one-hot writer: flat float4 index e covers enc[n][j0..j0+3],
// n = e>>8, j0 = (e&255)*4. grid-stride, 2048 blocks.
__global__ __launch_bounds__(256) void enc_write(const int* __restrict__ idx,
                                                 float* __restrict__ enc) {
    const int TOT = (N_PIX / 4) * K_CODES;   // 8388608 float4s
    int tid = blockIdx.x * 256 + threadIdx.x;
    float4* enc4 = reinterpret_cast<float4*>(enc);
    for (int e = tid; e < TOT; e += 2048 * 256) {
        int n  = e >> 8;
        int j0 = (e & 255) << 2;
        int ir = idx[n];                 // row-uniform -> L1/L2 broadcast
        float4 v;
        v.x = (ir == j0 + 0) ? 1.0f : 0.0f;
        v.y = (ir == j0 + 1) ? 1.0f : 0.0f;
        v.z = (ir == j0 + 2) ? 1.0f : 0.0f;
        v.w = (ir == j0 + 3) ? 1.0f : 0.0f;
        enc4[e] = v;
    }
}

extern "C" void kernel_launch(void* const* d_in, const int* in_sizes, int n_in,
                              void* d_out, int out_size, void* d_ws, size_t ws_size,
                              hipStream_t stream) {
    const float* x  = (const float*)d_in[0];
    const float* cb = (const float*)d_in[1];

    float* c2  = (float*)d_ws;
    int*   idx = (int*)((char*)d_ws + 4096);

    float* enc   = (float*)d_out;                           // [32768, 1024]
    float* quant = (float*)d_out + (size_t)N_PIX * K_CODES; // [32, 64, 32, 32]

    c2_kernel<<<K_CODES / 256, 256, 0, stream>>>(cb, c2);
    argmin_tile<<<N_PIX / BPIX, 512, 0, stream>>>(x, cb, c2, idx, quant);
    enc_write<<<2048, 256, 0, stream>>>(idx, enc);
}